// Round 1
// baseline (295.569 us; speedup 1.0000x reference)
//
#include <hip/hip_runtime.h>
#include <math.h>

typedef unsigned short u16;
typedef unsigned int   u32;
typedef unsigned long long u64;

#define NATOMS 8192
#define GRAPHS 64
#define KNN    32
#define NGAUSS 50
#define HID    128
#define LAYERS 6
#define NTAB   4096
#define SA     136   // u16 stride, 272B rows (16B-aligned, 4-bank row shift)
#define SW1    72    // u16 stride for staged mw1 rows
#define SH     132   // f32 stride, 528B rows (16B-aligned)

typedef __attribute__((ext_vector_type(8))) short bf16x8;
typedef __attribute__((ext_vector_type(4))) float f32x4;

__device__ __forceinline__ float bf2f(u16 v) {
    return __uint_as_float(((u32)v) << 16);
}
__device__ __forceinline__ u16 f2bf(float f) {
    u32 u = __float_as_uint(f);
    u32 lsb = (u >> 16) & 1u;
    u += 0x7fffu + lsb;
    return (u16)(u >> 16);
}
__device__ __forceinline__ u32 pkbf(float lo, float hi) {
#if __has_builtin(__builtin_amdgcn_cvt_pk_bf16_f32)
    auto r = __builtin_amdgcn_cvt_pk_bf16_f32(lo, hi);
    u32 u; __builtin_memcpy(&u, &r, 4); return u;
#else
    return (u32)f2bf(lo) | ((u32)f2bf(hi) << 16);
#endif
}
__device__ __forceinline__ float silu_f(float x) {
    return x * __builtin_amdgcn_rcpf(1.0f + __expf(-x));
}
__device__ __forceinline__ bf16x8 ldfrag(const u16* p) {
    return *(const bf16x8*)__builtin_assume_aligned(p, 16);
}
__device__ __forceinline__ u64 shfl_xor_u64(u64 v, int mask) {
    u32 lo = (u32)v, hi = (u32)(v >> 32);
    lo = (u32)__shfl_xor((int)lo, mask, 64);
    hi = (u32)__shfl_xor((int)hi, mask, 64);
    return ((u64)hi << 32) | lo;
}
__device__ __forceinline__ float ldf(const void* p, int i, bool f32in) {
    return f32in ? ((const float*)p)[i] : bf2f(((const u16*)p)[i]);
}
union U8 { bf16x8 v; u32 w[4]; };

// ---------------------------------------------------------------------------
// K0: dtype probe + zero rev_cnt/gsum/done (folds memset dispatches).
// ---------------------------------------------------------------------------
__global__ void probe_kernel(const u16* __restrict__ raw, int* __restrict__ flag,
                             int* __restrict__ rev_cnt, float* __restrict__ gsum,
                             int* __restrict__ done_cnt) {
    __shared__ int s;
    int t = threadIdx.x;
    if (t == 0) s = 0;
    __syncthreads();
    float x = bf2f(raw[2 * t]);
    if (!(fabsf(x) < 1000.0f)) atomicOr(&s, 1);
    for (int i = t; i < NATOMS; i += 256) rev_cnt[i] = 0;
    if (t < GRAPHS) gsum[t] = 0.0f;
    if (t == 0) *done_cnt = 0;
    __syncthreads();
    if (t == 0) *flag = s;
}

// ---------------------------------------------------------------------------
// K1: merged setup — build_graph (2048 blocks, raw pos w/ inline dtype conv)
// + weight prep (1344 blocks) + fp32 ingest (tail blocks). No LDS in any
// branch, so occupancy is unconstrained; the three sub-kernels overlap.
// ---------------------------------------------------------------------------
#define NARR 9
struct IngestDesc {
    const void* src[NARR];
    void*       dst[NARR];
    int         n[NARR];
};

#define NB_BUILD 2048
#define NB_PREP  1344

__launch_bounds__(256)
__global__ void setup_kernel(const void* __restrict__ pos,
                             const void* __restrict__ l1w, const void* __restrict__ l2w,
                             const void* __restrict__ mw2, const void* __restrict__ mw1,
                             u16* __restrict__ l1wt, u16* __restrict__ l2wt,
                             u16* __restrict__ mw2t, u16* __restrict__ mw1t,
                             IngestDesc d, int total_ing,
                             const int* __restrict__ flag,
                             int* __restrict__ rev_cnt, int2* __restrict__ rev_si) {
    int bid = blockIdx.x;
    bool f32in = (*flag != 0);
    if (bid < NB_BUILD) {
        // --- graph build: one wave per center, bitonic sort of 128 keys ---
        int wv = threadIdx.x >> 6, lane = threadIdx.x & 63;
        int t = bid * 4 + wv;
        int tl = t & 127;
        int base = t & ~127;
        float cx = ldf(pos, t * 3 + 0, f32in);
        float cy = ldf(pos, t * 3 + 1, f32in);
        float cz = ldf(pos, t * 3 + 2, f32in);
        u64 key[2];
#pragma unroll
        for (int c = 0; c < 2; ++c) {
            int j = lane + c * 64;
            float jx = ldf(pos, (base + j) * 3 + 0, f32in);
            float jy = ldf(pos, (base + j) * 3 + 1, f32in);
            float jz = ldf(pos, (base + j) * 3 + 2, f32in);
            float dx = __fsub_rn(cx, jx);
            float dy = __fsub_rn(cy, jy);
            float dz = __fsub_rn(cz, jz);
            float d2 = __fadd_rn(__fadd_rn(__fmul_rn(dx, dx), __fmul_rn(dy, dy)),
                                 __fmul_rn(dz, dz));
            bool valid = (j != tl) && (d2 < 100.0f);
            key[c] = valid ? ((((u64)__float_as_uint(d2)) << 32) | (u32)j) : ~0ULL;
        }
#pragma unroll
        for (int k = 2; k <= 128; k <<= 1) {
#pragma unroll
            for (int j = k >> 1; j > 0; j >>= 1) {
                if (j == 64) {
                    u64 lo = key[0] < key[1] ? key[0] : key[1];
                    u64 hi = key[0] < key[1] ? key[1] : key[0];
                    key[0] = lo; key[1] = hi;
                } else {
#pragma unroll
                    for (int r = 0; r < 2; ++r) {
                        u64 o = shfl_xor_u64(key[r], j);
                        u32 ii = (u32)(r * 64 + lane);
                        bool dir = ((ii & (u32)k) == 0);
                        bool lower = ((ii & (u32)j) == 0);
                        bool keep_min = (dir == lower);
                        bool less = key[r] < o;
                        key[r] = (less == keep_min) ? key[r] : o;
                    }
                }
            }
        }
        if (lane < KNN) {
            u64 m = key[0];
            if (m != ~0ULL) {
                float d2 = __uint_as_float((u32)(m >> 32));
                float dd = __fsqrt_rn(d2);
                if (dd < 10.0f) {
                    float u = dd * ((float)(NTAB - 1) / 10.0f);
                    int i0 = (int)(u + 0.5f);          // nearest
                    if (i0 > NTAB - 1) i0 = NTAB - 1;
                    int jn = base + (int)(m & 0xffffffffu);
                    int p = atomicAdd(&rev_cnt[jn], 1);
                    rev_si[(size_t)jn * 128 + p] = make_int2(t, i0);
                }
            }
        }
    } else if (bid < NB_BUILD + NB_PREP) {
        // --- weight prep: transpose l1w/l2w/mw2 -> [n][k] bf16; mw1 -> [n][64]
        int gid = (bid - NB_BUILD) * 256 + threadIdx.x;
        if (gid < 3 * 98304) {
            int seg = gid / 98304;
            int tt = gid % 98304;
            int l = tt >> 14;
            int n = (tt >> 7) & 127;
            int k = tt & 127;
            const void* src = (seg == 0) ? l1w : ((seg == 1) ? l2w : mw2);
            u16* dst = (seg == 0) ? l1wt : ((seg == 1) ? l2wt : mw2t);
            int si = l * 16384 + k * 128 + n;
            float v = f32in ? ((const float*)src)[si] : bf2f(((const u16*)src)[si]);
            dst[tt] = f2bf(v);
        } else {
            int tt = gid - 3 * 98304;
            if (tt < 49152) {
                int l = tt >> 13;
                int n = (tt >> 6) & 127;
                int k = tt & 63;
                float v = 0.0f;
                if (k < 50) {
                    int si = l * 6400 + k * 128 + n;
                    v = f32in ? ((const float*)mw1)[si] : bf2f(((const u16*)mw1)[si]);
                }
                mw1t[tt] = f2bf(v);
            }
        }
    } else {
        // --- ingest small arrays to fp32 canonical ---
        int gid = (bid - NB_BUILD - NB_PREP) * 256 + threadIdx.x;
        if (gid < total_ing) {
            int a = 0, off = gid;
            while (off >= d.n[a]) { off -= d.n[a]; ++a; }
            float v = f32in ? ((const float*)d.src[a])[off]
                            : bf2f(((const u16*)d.src[a])[off]);
            ((float*)d.dst[a])[off] = v;
        }
    }
}

// ---------------------------------------------------------------------------
// K4a: filter tables via MFMA (unchanged from R18).
// ---------------------------------------------------------------------------
__launch_bounds__(256)
__global__ void vtab_kernel(const u16* __restrict__ mw1t,   // [6][128][64]
                            const u16* __restrict__ mw2t,   // [6][128][128]
                            const float* __restrict__ b1,   // [6][128]
                            const float* __restrict__ b2,   // [6][128]
                            u32* __restrict__ pk) {         // [6][NTAB][64]
    __shared__ u16 s_t1[128 * SA];
    __shared__ u16 s_w1[128 * SW1];
    __shared__ u16 s_w2[128 * SA];
    int tid = threadIdx.x;
    int l = blockIdx.x / (NTAB / 128);
    int rbase = (blockIdx.x % (NTAB / 128)) * 128;
    {
        const uint4* g1 = (const uint4*)(mw1t + (size_t)l * 8192);
#pragma unroll
        for (int p = 0; p < 4; ++p) {
            int q = tid + p * 256;
            int row = q >> 3, c8 = (q & 7) * 8;
            *(uint4*)&s_w1[row * SW1 + c8] = g1[q];
        }
        const uint4* g2 = (const uint4*)(mw2t + (size_t)l * 16384);
#pragma unroll
        for (int p = 0; p < 8; ++p) {
            int q = tid + p * 256;
            int row = q >> 4, c8 = (q & 15) * 8;
            *(uint4*)&s_w2[row * SA + c8] = g2[q];
        }
    }
    __syncthreads();

    int wv = tid >> 6, lane = tid & 63;
    int quad = lane >> 4, lr = lane & 15;
    int m0 = wv * 32;

    {
        const float wgi = 49.0f / 10.0f;
        const float dstep = 10.0f / (float)(NTAB - 1);
        U8 afr[2][2];
#pragma unroll
        for (int mt = 0; mt < 2; ++mt) {
            float d = (float)(rbase + m0 + mt * 16 + lr) * dstep;
            float u = d * wgi;
#pragma unroll
            for (int kki = 0; kki < 2; ++kki) {
                float t0 = u - (float)(quad * 8) - (float)(kki * 32);
                float vj[8];
#pragma unroll
                for (int j = 0; j < 8; ++j) {
                    float tt = t0 - (float)j;
                    float e = __expf(-0.5f * tt * tt);
                    if (kki == 1 && (quad * 8 + j) >= 18) e = 0.0f;
                    vj[j] = e;
                }
#pragma unroll
                for (int p = 0; p < 4; ++p)
                    afr[mt][kki].w[p] = pkbf(vj[2 * p], vj[2 * p + 1]);
            }
        }
        f32x4 accA[2][8];
#pragma unroll
        for (int mt = 0; mt < 2; ++mt)
#pragma unroll
            for (int nt = 0; nt < 8; ++nt) accA[mt][nt] = (f32x4){0.f, 0.f, 0.f, 0.f};
#pragma unroll
        for (int kki = 0; kki < 2; ++kki) {
#pragma unroll
            for (int nt = 0; nt < 8; ++nt) {
                bf16x8 b = ldfrag(&s_w1[(nt * 16 + lr) * SW1 + kki * 32 + quad * 8]);
                accA[0][nt] = __builtin_amdgcn_mfma_f32_16x16x32_bf16(afr[0][kki].v, b, accA[0][nt], 0, 0, 0);
                accA[1][nt] = __builtin_amdgcn_mfma_f32_16x16x32_bf16(afr[1][kki].v, b, accA[1][nt], 0, 0, 0);
            }
        }
#pragma unroll
        for (int mt = 0; mt < 2; ++mt) {
            int r0 = m0 + mt * 16 + quad * 4;
            u16* tp0 = &s_t1[r0 * SA + lr];
#pragma unroll
            for (int nt = 0; nt < 8; ++nt) {
                int col = nt * 16;
                float bb = b1[l * 128 + col + lr];
                u32 p01 = pkbf(silu_f(accA[mt][nt][0] + bb),
                               silu_f(accA[mt][nt][1] + bb));
                u32 p23 = pkbf(silu_f(accA[mt][nt][2] + bb),
                               silu_f(accA[mt][nt][3] + bb));
                u16* tp = tp0 + col;
                tp[0]      = (u16)p01;
                tp[SA]     = (u16)(p01 >> 16);
                tp[2 * SA] = (u16)p23;
                tp[3 * SA] = (u16)(p23 >> 16);
            }
        }
    }
    // no barrier: Phase B reads only this wave's own 32 t1 rows
    {
        f32x4 accB[2][8];
#pragma unroll
        for (int mt = 0; mt < 2; ++mt)
#pragma unroll
            for (int nt = 0; nt < 8; ++nt) accB[mt][nt] = (f32x4){0.f, 0.f, 0.f, 0.f};
#pragma unroll
        for (int kk = 0; kk < 128; kk += 32) {
            bf16x8 a0 = ldfrag(&s_t1[(m0 + lr)      * SA + kk + quad * 8]);
            bf16x8 a1 = ldfrag(&s_t1[(m0 + 16 + lr) * SA + kk + quad * 8]);
#pragma unroll
            for (int nt = 0; nt < 8; ++nt) {
                bf16x8 b = ldfrag(&s_w2[(nt * 16 + lr) * SA + kk + quad * 8]);
                accB[0][nt] = __builtin_amdgcn_mfma_f32_16x16x32_bf16(a0, b, accB[0][nt], 0, 0, 0);
                accB[1][nt] = __builtin_amdgcn_mfma_f32_16x16x32_bf16(a1, b, accB[1][nt], 0, 0, 0);
            }
        }
        const float dstep = 10.0f / (float)(NTAB - 1);
#pragma unroll
        for (int mt = 0; mt < 2; ++mt) {
            int r0 = m0 + mt * 16 + quad * 4;
            float cv[4];
#pragma unroll
            for (int r = 0; r < 4; ++r) {
                float d = (float)(rbase + r0 + r) * dstep;
                cv[r] = 0.5f * (cosf(d * 3.14159265f / 10.0f) + 1.0f);
            }
#pragma unroll
            for (int nt = 0; nt < 8; ++nt) {
                int col = nt * 16 + lr;
                float bb = b2[l * 128 + col];
#pragma unroll
                for (int r = 0; r < 4; ++r) {
                    float val = (accB[mt][nt][r] + bb) * cv[r];
                    float oth = __shfl_xor(val, 1, 64);
                    if ((lr & 1) == 0) {
                        int row = rbase + r0 + r;
                        pk[((size_t)l * NTAB + row) * 64 + (col >> 1)] =
                            pkbf(val, oth);
                    }
                }
            }
        }
    }
}

// ---------------------------------------------------------------------------
// K3a: initial gemm0 — xj(0) = emb[z] @ l1w(0) + b1(0), bf16 out (unchanged).
// ---------------------------------------------------------------------------
__launch_bounds__(256)
__global__ void gemm0_kernel(const int* __restrict__ z,
                             const float* __restrict__ emb,
                             const u16* __restrict__ Bt,
                             const float* __restrict__ bias,
                             u16* __restrict__ xjb) {
    __shared__ u16 s_a[16 * SA];
    __shared__ float s_bias[128];
    int tid = threadIdx.x;
    int row0 = blockIdx.x * 16;
#pragma unroll
    for (int p = 0; p < 2; ++p) {
        int q = tid + p * 256;
        int r = q >> 5, c4 = (q & 31) * 4;
        const float* src = emb + (size_t)z[row0 + r] * 128;
        float4 v = *(const float4*)(src + c4);
        u32* dd = (u32*)&s_a[r * SA + c4];
        dd[0] = pkbf(v.x, v.y); dd[1] = pkbf(v.z, v.w);
    }
    if (tid < 128) s_bias[tid] = bias[tid];
    __syncthreads();
    int wv = tid >> 6, lane = tid & 63;
    int quad = lane >> 4, lr = lane & 15;
    int n0 = wv * 32;
    f32x4 acc[2];
#pragma unroll
    for (int nt = 0; nt < 2; ++nt) acc[nt] = (f32x4){0.f, 0.f, 0.f, 0.f};
#pragma unroll
    for (int kk = 0; kk < 128; kk += 32) {
        bf16x8 a = ldfrag(&s_a[lr * SA + kk + quad * 8]);
#pragma unroll
        for (int nt = 0; nt < 2; ++nt) {
            bf16x8 b = ldfrag(Bt + (n0 + nt * 16 + lr) * 128 + kk + quad * 8);
            acc[nt] = __builtin_amdgcn_mfma_f32_16x16x32_bf16(a, b, acc[nt], 0, 0, 0);
        }
    }
#pragma unroll
    for (int nt = 0; nt < 2; ++nt)
#pragma unroll
        for (int r = 0; r < 4; ++r) {
            int col = n0 + nt * 16 + lr;
            xjb[(size_t)(row0 + quad * 4 + r) * 128 + col] =
                f2bf(acc[nt][r] + s_bias[col]);
        }
}

// ---------------------------------------------------------------------------
// K5: fused layer — agg (4 receivers/wave, hi/lo split straight from regs
// into LDS) + h update + next-xj GEMM. LAST=1 additionally fuses the output
// head (consumes s_h directly; h never round-trips) and finalize via a
// last-block-done ticket with agent-scope atomics.
// xjb is double-buffered across layers (agg reads other blocks' rows while
// tail writes own rows -> in/out must differ).
// ---------------------------------------------------------------------------
template <int EMB, int LAST>
__launch_bounds__(256)
__global__ void layer_fused_kernel(const int* __restrict__ rev_cnt,
                                   const int2* __restrict__ rev_si,
                                   const u32* __restrict__ pk,
                                   const u16* __restrict__ xjb_in,
                                   float* __restrict__ h,
                                   const int* __restrict__ z,
                                   const float* __restrict__ emb,
                                   const u16* __restrict__ B2t,
                                   const float* __restrict__ b2,
                                   const u16* __restrict__ B1n,
                                   const float* __restrict__ b1n,
                                   u16* __restrict__ xjb_out,
                                   const float* __restrict__ ow1,
                                   const float* __restrict__ ob1,
                                   const float* __restrict__ ow2,
                                   const float* __restrict__ ob2,
                                   float* __restrict__ gsum,
                                   int* __restrict__ done_cnt,
                                   void* __restrict__ out,
                                   const int* __restrict__ flag) {
    __shared__ u16 s_ahi[16 * SA];
    __shared__ u16 s_alo[16 * SA];
    __shared__ float s_h[16 * SH];
    __shared__ float s_b2[128], s_b1[128];
    __shared__ float s_w[LAST ? 128 * 64 : 1];
    __shared__ float s_sum;
    __shared__ int s_last;
    int tid = threadIdx.x;
    int row0 = blockIdx.x * 16;
    int wv = tid >> 6, lane = tid & 63;

    if (tid < 128) {
        s_b2[tid] = b2[tid];
        if (!LAST) s_b1[tid] = b1n[tid];
    }
    if (LAST) {
        if (tid == 0) s_sum = 0.0f;
        const float4* src = (const float4*)ow1;
        float4* dst = (float4*)s_w;
#pragma unroll
        for (int p = 0; p < 8; ++p) dst[tid + p * 256] = src[tid + p * 256];
    }

    // ---- Phase 1: aggregate (R15-proven inner loop), hi/lo split from regs
    {
        int c2 = lane * 2;
        for (int rr = 0; rr < 4; ++rr) {
            int row = wv * 4 + rr;
            int j = row0 + row;
            int deg = rev_cnt[j];
            const int2* si = rev_si + (size_t)j * 128;
            float a0 = 0.f, a1 = 0.f, b0 = 0.f, b1v = 0.f;
            float c0 = 0.f, c1 = 0.f, d0 = 0.f, d1 = 0.f;
            int it = 0;
            for (; it + 8 <= deg; it += 8) {
                u32 tq[8], xq[8];
#pragma unroll
                for (int q = 0; q < 8; ++q) {
                    int2 s = si[it + q];
                    tq[q] = pk[(size_t)s.y * 64 + lane];
                    xq[q] = *(const u32*)(xjb_in + (size_t)s.x * 128 + c2);
                }
#pragma unroll
                for (int q = 0; q < 8; ++q) {
                    float v0 = bf2f((u16)tq[q]) * bf2f((u16)xq[q]);
                    float v1 = bf2f((u16)(tq[q] >> 16)) * bf2f((u16)(xq[q] >> 16));
                    switch (q & 3) {
                        case 0: a0 += v0; a1 += v1; break;
                        case 1: b0 += v0; b1v += v1; break;
                        case 2: c0 += v0; c1 += v1; break;
                        default: d0 += v0; d1 += v1; break;
                    }
                }
            }
            for (; it + 4 <= deg; it += 4) {
                u32 tq[4], xq[4];
#pragma unroll
                for (int q = 0; q < 4; ++q) {
                    int2 s = si[it + q];
                    tq[q] = pk[(size_t)s.y * 64 + lane];
                    xq[q] = *(const u32*)(xjb_in + (size_t)s.x * 128 + c2);
                }
#pragma unroll
                for (int q = 0; q < 4; ++q) {
                    float v0 = bf2f((u16)tq[q]) * bf2f((u16)xq[q]);
                    float v1 = bf2f((u16)(tq[q] >> 16)) * bf2f((u16)(xq[q] >> 16));
                    if (q == 0) { a0 += v0; a1 += v1; }
                    else if (q == 1) { b0 += v0; b1v += v1; }
                    else if (q == 2) { c0 += v0; c1 += v1; }
                    else { d0 += v0; d1 += v1; }
                }
            }
            for (; it < deg; ++it) {
                int2 s = si[it];
                u32 tq = pk[(size_t)s.y * 64 + lane];
                u32 xq = *(const u32*)(xjb_in + (size_t)s.x * 128 + c2);
                a0 += bf2f((u16)tq) * bf2f((u16)xq);
                a1 += bf2f((u16)(tq >> 16)) * bf2f((u16)(xq >> 16));
            }
            float sx = (a0 + b0) + (c0 + d0);
            float sy = (a1 + b1v) + (c1 + d1);
            u32 hp = pkbf(sx, sy);
            u32 lp = pkbf(sx - bf2f((u16)hp), sy - bf2f((u16)(hp >> 16)));
            *(u32*)&s_ahi[row * SA + c2] = hp;
            *(u32*)&s_alo[row * SA + c2] = lp;
        }
    }
    __syncthreads();

    // ---- Phase 2: h_new = h_old + silu(agg @ l2w + b2)  [hi/lo split A]
    int quad = lane >> 4, lr = lane & 15;
    int n0 = wv * 32;
    f32x4 acc[2];
#pragma unroll
    for (int nt = 0; nt < 2; ++nt) acc[nt] = (f32x4){0.f, 0.f, 0.f, 0.f};
#pragma unroll
    for (int kk = 0; kk < 128; kk += 32) {
        bf16x8 ah = ldfrag(&s_ahi[lr * SA + kk + quad * 8]);
        bf16x8 al = ldfrag(&s_alo[lr * SA + kk + quad * 8]);
#pragma unroll
        for (int nt = 0; nt < 2; ++nt) {
            bf16x8 b = ldfrag(B2t + (n0 + nt * 16 + lr) * 128 + kk + quad * 8);
            acc[nt] = __builtin_amdgcn_mfma_f32_16x16x32_bf16(ah, b, acc[nt], 0, 0, 0);
            acc[nt] = __builtin_amdgcn_mfma_f32_16x16x32_bf16(al, b, acc[nt], 0, 0, 0);
        }
    }
#pragma unroll
    for (int nt = 0; nt < 2; ++nt)
#pragma unroll
        for (int r = 0; r < 4; ++r) {
            int row = quad * 4 + r;
            int col = n0 + nt * 16 + lr;
            size_t off = (size_t)(row0 + row) * 128 + col;
            float hold = EMB ? emb[(size_t)z[row0 + row] * 128 + col] : h[off];
            float hn = hold + silu_f(acc[nt][r] + s_b2[col]);
            if (!LAST) h[off] = hn;
            s_h[row * SH + col] = hn;
        }
    __syncthreads();

    if (!LAST) {
        // ---- Phase 3: xj(l+1) = h_new @ l1w(l+1) + b1(l+1)
        f32x4 ac2[2];
#pragma unroll
        for (int nt = 0; nt < 2; ++nt) ac2[nt] = (f32x4){0.f, 0.f, 0.f, 0.f};
#pragma unroll
        for (int kk = 0; kk < 128; kk += 32) {
            const float* ap = &s_h[lr * SH + kk + quad * 8];
            float4 v0 = *(const float4*)ap;
            float4 v1 = *(const float4*)(ap + 4);
            U8 a;
            a.w[0] = pkbf(v0.x, v0.y); a.w[1] = pkbf(v0.z, v0.w);
            a.w[2] = pkbf(v1.x, v1.y); a.w[3] = pkbf(v1.z, v1.w);
#pragma unroll
            for (int nt = 0; nt < 2; ++nt) {
                bf16x8 b = ldfrag(B1n + (n0 + nt * 16 + lr) * 128 + kk + quad * 8);
                ac2[nt] = __builtin_amdgcn_mfma_f32_16x16x32_bf16(a.v, b, ac2[nt], 0, 0, 0);
            }
        }
#pragma unroll
        for (int nt = 0; nt < 2; ++nt)
#pragma unroll
            for (int r = 0; r < 4; ++r) {
                int col = n0 + nt * 16 + lr;
                xjb_out[(size_t)(row0 + quad * 4 + r) * 128 + col] =
                    f2bf(ac2[nt][r] + s_b1[col]);
            }
    } else {
        // ---- Phase 3 (LAST): output head from s_h, then last-block finalize
        int atom = tid >> 4, cg = tid & 15;
        const float* hr = &s_h[atom * SH];
        const float4* w4 = (const float4*)s_w;
        float4 a4 = {0.f, 0.f, 0.f, 0.f};
#pragma unroll 8
        for (int f = 0; f < 128; ++f) {
            float hv = hr[f];
            float4 w = w4[f * 16 + cg];
            a4.x += hv * w.x; a4.y += hv * w.y;
            a4.z += hv * w.z; a4.w += hv * w.w;
        }
        int c0i = cg * 4;
        float v = silu_f(a4.x + ob1[c0i + 0]) * ow2[c0i + 0]
                + silu_f(a4.y + ob1[c0i + 1]) * ow2[c0i + 1]
                + silu_f(a4.z + ob1[c0i + 2]) * ow2[c0i + 2]
                + silu_f(a4.w + ob1[c0i + 3]) * ow2[c0i + 3];
        v += __shfl_xor(v, 1, 64);
        v += __shfl_xor(v, 2, 64);
        v += __shfl_xor(v, 4, 64);
        v += __shfl_xor(v, 8, 64);
        if ((tid & 15) == 0) atomicAdd(&s_sum, v + ob2[0]);
        __syncthreads();
        if (tid == 0) {
            atomicAdd(&gsum[row0 >> 7], s_sum);
            __threadfence();
            int tk = __hip_atomic_fetch_add(done_cnt, 1, __ATOMIC_ACQ_REL,
                                            __HIP_MEMORY_SCOPE_AGENT);
            s_last = (tk == (NATOMS / 16) - 1);
        }
        __syncthreads();
        if (s_last && tid < GRAPHS) {
            float g = __hip_atomic_load(&gsum[tid], __ATOMIC_RELAXED,
                                        __HIP_MEMORY_SCOPE_AGENT);
            if (*flag) ((float*)out)[tid] = g;
            else       ((u16*)out)[tid]   = f2bf(g);
        }
    }
}

// ---------------------------------------------------------------------------
extern "C" void kernel_launch(void* const* d_in, const int* in_sizes, int n_in,
                              void* d_out, int out_size, void* d_ws, size_t ws_size,
                              hipStream_t stream) {
    const void* pos  = d_in[0];
    const int*  z    = (const int*)d_in[1];
    // d_in[2] = batch (implicit: graph = i >> 7)
    const void* emb  = d_in[3];
    const void* mw1  = d_in[4];
    const void* mb1  = d_in[5];
    const void* mw2  = d_in[6];
    const void* mb2  = d_in[7];
    const void* l1w  = d_in[8];
    const void* l1b  = d_in[9];
    const void* l2w  = d_in[10];
    const void* l2b  = d_in[11];
    const void* ow1  = d_in[12];
    const void* ob1  = d_in[13];
    const void* ow2  = d_in[14];
    const void* ob2  = d_in[15];

    char* ws = (char*)d_ws;
    const size_t KB = 1024, MB = 1048576;
    int*   w_flag  = (int*)  (ws);
    int*   w_done  = (int*)  (ws + 64);
    float* c_emb   = (float*)(ws + 112 * KB);
    float* c_mb1   = (float*)(ws + 168 * KB);
    float* c_mb2   = (float*)(ws + 176 * KB);
    float* c_l1b   = (float*)(ws + 184 * KB);
    float* c_l2b   = (float*)(ws + 192 * KB);
    float* c_ow1   = (float*)(ws + 200 * KB);
    float* c_ob1   = (float*)(ws + 236 * KB);
    float* c_ow2   = (float*)(ws + 240 * KB);
    float* c_ob2   = (float*)(ws + 244 * KB);
    float* w_gsum  = (float*)(ws + 248 * KB);
    u16*   c_l1wt  = (u16*)  (ws + 256 * KB);   // 192 KB
    u16*   c_l2wt  = (u16*)  (ws + 448 * KB);   // 192 KB
    u16*   c_mw2t  = (u16*)  (ws + 640 * KB);   // 192 KB
    u16*   c_mw1t  = (u16*)  (ws + 832 * KB);   // 96 KB
    int*   rev_cnt = (int*)  (ws + 2  * MB);    // 32 KB
    int2*  rev_si  = (int2*) (ws + 3  * MB);    // 8 MB
    float* w_h     = (float*)(ws + 11 * MB);    // 4 MB
    u16*   w_xjbA  = (u16*)  (ws + 15 * MB);    // 2 MB
    u16*   w_xjbB  = (u16*)  (ws + 17 * MB);    // 2 MB
    u32*   w_pk    = (u32*)  (ws + 21 * MB);    // 6 MB

    probe_kernel<<<1, 256, 0, stream>>>((const u16*)emb, w_flag, rev_cnt,
                                        w_gsum, w_done);

    IngestDesc dsc;
    const void* srcs[NARR] = {emb, mb1, mb2, l1b, l2b, ow1, ob1, ow2, ob2};
    void* dsts[NARR] = {c_emb, c_mb1, c_mb2, c_l1b, c_l2b, c_ow1, c_ob1,
                        c_ow2, c_ob2};
    int ns_[NARR] = {12800, 768, 768, 768, 768, 8192, 64, 64, 1};
    int total = 0;
    for (int a = 0; a < NARR; ++a) {
        dsc.src[a] = srcs[a]; dsc.dst[a] = dsts[a]; dsc.n[a] = ns_[a];
        total += ns_[a];
    }
    int nb_ing = (total + 255) / 256;
    setup_kernel<<<NB_BUILD + NB_PREP + nb_ing, 256, 0, stream>>>(
        pos, l1w, l2w, mw2, mw1, c_l1wt, c_l2wt, c_mw2t, c_mw1t,
        dsc, total, w_flag, rev_cnt, rev_si);

    vtab_kernel<<<LAYERS * NTAB / 128, 256, 0, stream>>>(
        c_mw1t, c_mw2t, c_mb1, c_mb2, w_pk);

    gemm0_kernel<<<NATOMS / 16, 256, 0, stream>>>(z, c_emb, c_l1wt, c_l1b, w_xjbA);

    for (int l = 0; l < LAYERS; ++l) {
        u16* xin  = (l & 1) ? w_xjbB : w_xjbA;
        u16* xout = (l & 1) ? w_xjbA : w_xjbB;
        const u16* B2 = c_l2wt + (size_t)l * 16384;
        const float* b2 = c_l2b + (size_t)l * 128;
        const u16* B1n = c_l1wt + (size_t)(l + 1) * 16384;
        const float* b1n = c_l1b + (size_t)(l + 1) * 128;
        const u32* pkl = w_pk + (size_t)l * NTAB * 64;
        if (l == 0)
            layer_fused_kernel<1, 0><<<NATOMS / 16, 256, 0, stream>>>(
                rev_cnt, rev_si, pkl, xin, w_h, z, c_emb, B2, b2, B1n, b1n, xout,
                nullptr, nullptr, nullptr, nullptr, nullptr, nullptr, nullptr,
                nullptr);
        else if (l < LAYERS - 1)
            layer_fused_kernel<0, 0><<<NATOMS / 16, 256, 0, stream>>>(
                rev_cnt, rev_si, pkl, xin, w_h, z, c_emb, B2, b2, B1n, b1n, xout,
                nullptr, nullptr, nullptr, nullptr, nullptr, nullptr, nullptr,
                nullptr);
        else
            layer_fused_kernel<0, 1><<<NATOMS / 16, 256, 0, stream>>>(
                rev_cnt, rev_si, pkl, xin, w_h, z, c_emb, B2, b2, nullptr,
                nullptr, nullptr, c_ow1, c_ob1, c_ow2, c_ob2, w_gsum, w_done,
                d_out, w_flag);
    }
}

// Round 2
// 270.932 us; speedup vs baseline: 1.0909x; 1.0909x over previous
//
#include <hip/hip_runtime.h>
#include <math.h>

typedef unsigned short u16;
typedef unsigned int   u32;
typedef unsigned long long u64;

#define NATOMS 8192
#define GRAPHS 64
#define KNN    32
#define NGAUSS 50
#define HID    128
#define LAYERS 6
#define NTAB   4096
#define SA     136   // u16 stride, 272B rows (16B-aligned, 4-bank row shift)
#define SW1    72    // u16 stride for staged mw1 rows
#define SH     132   // f32 stride, 528B rows (16B-aligned)

typedef __attribute__((ext_vector_type(8))) short bf16x8;
typedef __attribute__((ext_vector_type(4))) float f32x4;

__device__ __forceinline__ float bf2f(u16 v) {
    return __uint_as_float(((u32)v) << 16);
}
__device__ __forceinline__ u16 f2bf(float f) {
    u32 u = __float_as_uint(f);
    u32 lsb = (u >> 16) & 1u;
    u += 0x7fffu + lsb;
    return (u16)(u >> 16);
}
__device__ __forceinline__ u32 pkbf(float lo, float hi) {
#if __has_builtin(__builtin_amdgcn_cvt_pk_bf16_f32)
    auto r = __builtin_amdgcn_cvt_pk_bf16_f32(lo, hi);
    u32 u; __builtin_memcpy(&u, &r, 4); return u;
#else
    return (u32)f2bf(lo) | ((u32)f2bf(hi) << 16);
#endif
}
__device__ __forceinline__ float silu_f(float x) {
    return x * __builtin_amdgcn_rcpf(1.0f + __expf(-x));
}
__device__ __forceinline__ bf16x8 ldfrag(const u16* p) {
    return *(const bf16x8*)__builtin_assume_aligned(p, 16);
}
__device__ __forceinline__ u64 shfl_xor_u64(u64 v, int mask) {
    u32 lo = (u32)v, hi = (u32)(v >> 32);
    lo = (u32)__shfl_xor((int)lo, mask, 64);
    hi = (u32)__shfl_xor((int)hi, mask, 64);
    return ((u64)hi << 32) | lo;
}
__device__ __forceinline__ float ldf(const void* p, int i, bool f32in) {
    return f32in ? ((const float*)p)[i] : bf2f(((const u16*)p)[i]);
}
union U8 { bf16x8 v; u32 w[4]; };

// ---------------------------------------------------------------------------
// K0: dtype probe + zero rev_cnt/gsum/done (folds memset dispatches).
// ---------------------------------------------------------------------------
__global__ void probe_kernel(const u16* __restrict__ raw, int* __restrict__ flag,
                             int* __restrict__ rev_cnt, float* __restrict__ gsum,
                             int* __restrict__ done_cnt) {
    __shared__ int s;
    int t = threadIdx.x;
    if (t == 0) s = 0;
    __syncthreads();
    float x = bf2f(raw[2 * t]);
    if (!(fabsf(x) < 1000.0f)) atomicOr(&s, 1);
    for (int i = t; i < NATOMS; i += 256) rev_cnt[i] = 0;
    if (t < GRAPHS) gsum[t] = 0.0f;
    if (t == 0) *done_cnt = 0;
    __syncthreads();
    if (t == 0) *flag = s;
}

// ---------------------------------------------------------------------------
// K1: merged setup — build_graph + weight prep + fp32 ingest (round-1 form).
// ---------------------------------------------------------------------------
#define NARR 9
struct IngestDesc {
    const void* src[NARR];
    void*       dst[NARR];
    int         n[NARR];
};

#define NB_BUILD 2048
#define NB_PREP  1344

__launch_bounds__(256)
__global__ void setup_kernel(const void* __restrict__ pos,
                             const void* __restrict__ l1w, const void* __restrict__ l2w,
                             const void* __restrict__ mw2, const void* __restrict__ mw1,
                             u16* __restrict__ l1wt, u16* __restrict__ l2wt,
                             u16* __restrict__ mw2t, u16* __restrict__ mw1t,
                             IngestDesc d, int total_ing,
                             const int* __restrict__ flag,
                             int* __restrict__ rev_cnt, int2* __restrict__ rev_si) {
    int bid = blockIdx.x;
    bool f32in = (*flag != 0);
    if (bid < NB_BUILD) {
        int wv = threadIdx.x >> 6, lane = threadIdx.x & 63;
        int t = bid * 4 + wv;
        int tl = t & 127;
        int base = t & ~127;
        float cx = ldf(pos, t * 3 + 0, f32in);
        float cy = ldf(pos, t * 3 + 1, f32in);
        float cz = ldf(pos, t * 3 + 2, f32in);
        u64 key[2];
#pragma unroll
        for (int c = 0; c < 2; ++c) {
            int j = lane + c * 64;
            float jx = ldf(pos, (base + j) * 3 + 0, f32in);
            float jy = ldf(pos, (base + j) * 3 + 1, f32in);
            float jz = ldf(pos, (base + j) * 3 + 2, f32in);
            float dx = __fsub_rn(cx, jx);
            float dy = __fsub_rn(cy, jy);
            float dz = __fsub_rn(cz, jz);
            float d2 = __fadd_rn(__fadd_rn(__fmul_rn(dx, dx), __fmul_rn(dy, dy)),
                                 __fmul_rn(dz, dz));
            bool valid = (j != tl) && (d2 < 100.0f);
            key[c] = valid ? ((((u64)__float_as_uint(d2)) << 32) | (u32)j) : ~0ULL;
        }
#pragma unroll
        for (int k = 2; k <= 128; k <<= 1) {
#pragma unroll
            for (int j = k >> 1; j > 0; j >>= 1) {
                if (j == 64) {
                    u64 lo = key[0] < key[1] ? key[0] : key[1];
                    u64 hi = key[0] < key[1] ? key[1] : key[0];
                    key[0] = lo; key[1] = hi;
                } else {
#pragma unroll
                    for (int r = 0; r < 2; ++r) {
                        u64 o = shfl_xor_u64(key[r], j);
                        u32 ii = (u32)(r * 64 + lane);
                        bool dir = ((ii & (u32)k) == 0);
                        bool lower = ((ii & (u32)j) == 0);
                        bool keep_min = (dir == lower);
                        bool less = key[r] < o;
                        key[r] = (less == keep_min) ? key[r] : o;
                    }
                }
            }
        }
        if (lane < KNN) {
            u64 m = key[0];
            if (m != ~0ULL) {
                float d2 = __uint_as_float((u32)(m >> 32));
                float dd = __fsqrt_rn(d2);
                if (dd < 10.0f) {
                    float u = dd * ((float)(NTAB - 1) / 10.0f);
                    int i0 = (int)(u + 0.5f);          // nearest
                    if (i0 > NTAB - 1) i0 = NTAB - 1;
                    int jn = base + (int)(m & 0xffffffffu);
                    int p = atomicAdd(&rev_cnt[jn], 1);
                    rev_si[(size_t)jn * 128 + p] = make_int2(t, i0);
                }
            }
        }
    } else if (bid < NB_BUILD + NB_PREP) {
        int gid = (bid - NB_BUILD) * 256 + threadIdx.x;
        if (gid < 3 * 98304) {
            int seg = gid / 98304;
            int tt = gid % 98304;
            int l = tt >> 14;
            int n = (tt >> 7) & 127;
            int k = tt & 127;
            const void* src = (seg == 0) ? l1w : ((seg == 1) ? l2w : mw2);
            u16* dst = (seg == 0) ? l1wt : ((seg == 1) ? l2wt : mw2t);
            int si = l * 16384 + k * 128 + n;
            float v = f32in ? ((const float*)src)[si] : bf2f(((const u16*)src)[si]);
            dst[tt] = f2bf(v);
        } else {
            int tt = gid - 3 * 98304;
            if (tt < 49152) {
                int l = tt >> 13;
                int n = (tt >> 6) & 127;
                int k = tt & 63;
                float v = 0.0f;
                if (k < 50) {
                    int si = l * 6400 + k * 128 + n;
                    v = f32in ? ((const float*)mw1)[si] : bf2f(((const u16*)mw1)[si]);
                }
                mw1t[tt] = f2bf(v);
            }
        }
    } else {
        int gid = (bid - NB_BUILD - NB_PREP) * 256 + threadIdx.x;
        if (gid < total_ing) {
            int a = 0, off = gid;
            while (off >= d.n[a]) { off -= d.n[a]; ++a; }
            float v = f32in ? ((const float*)d.src[a])[off]
                            : bf2f(((const u16*)d.src[a])[off]);
            ((float*)d.dst[a])[off] = v;
        }
    }
}

// ---------------------------------------------------------------------------
// K4a: filter tables via MFMA (unchanged).
// ---------------------------------------------------------------------------
__launch_bounds__(256)
__global__ void vtab_kernel(const u16* __restrict__ mw1t,   // [6][128][64]
                            const u16* __restrict__ mw2t,   // [6][128][128]
                            const float* __restrict__ b1,   // [6][128]
                            const float* __restrict__ b2,   // [6][128]
                            u32* __restrict__ pk) {         // [6][NTAB][64]
    __shared__ u16 s_t1[128 * SA];
    __shared__ u16 s_w1[128 * SW1];
    __shared__ u16 s_w2[128 * SA];
    int tid = threadIdx.x;
    int l = blockIdx.x / (NTAB / 128);
    int rbase = (blockIdx.x % (NTAB / 128)) * 128;
    {
        const uint4* g1 = (const uint4*)(mw1t + (size_t)l * 8192);
#pragma unroll
        for (int p = 0; p < 4; ++p) {
            int q = tid + p * 256;
            int row = q >> 3, c8 = (q & 7) * 8;
            *(uint4*)&s_w1[row * SW1 + c8] = g1[q];
        }
        const uint4* g2 = (const uint4*)(mw2t + (size_t)l * 16384);
#pragma unroll
        for (int p = 0; p < 8; ++p) {
            int q = tid + p * 256;
            int row = q >> 4, c8 = (q & 15) * 8;
            *(uint4*)&s_w2[row * SA + c8] = g2[q];
        }
    }
    __syncthreads();

    int wv = tid >> 6, lane = tid & 63;
    int quad = lane >> 4, lr = lane & 15;
    int m0 = wv * 32;

    {
        const float wgi = 49.0f / 10.0f;
        const float dstep = 10.0f / (float)(NTAB - 1);
        U8 afr[2][2];
#pragma unroll
        for (int mt = 0; mt < 2; ++mt) {
            float d = (float)(rbase + m0 + mt * 16 + lr) * dstep;
            float u = d * wgi;
#pragma unroll
            for (int kki = 0; kki < 2; ++kki) {
                float t0 = u - (float)(quad * 8) - (float)(kki * 32);
                float vj[8];
#pragma unroll
                for (int j = 0; j < 8; ++j) {
                    float tt = t0 - (float)j;
                    float e = __expf(-0.5f * tt * tt);
                    if (kki == 1 && (quad * 8 + j) >= 18) e = 0.0f;
                    vj[j] = e;
                }
#pragma unroll
                for (int p = 0; p < 4; ++p)
                    afr[mt][kki].w[p] = pkbf(vj[2 * p], vj[2 * p + 1]);
            }
        }
        f32x4 accA[2][8];
#pragma unroll
        for (int mt = 0; mt < 2; ++mt)
#pragma unroll
            for (int nt = 0; nt < 8; ++nt) accA[mt][nt] = (f32x4){0.f, 0.f, 0.f, 0.f};
#pragma unroll
        for (int kki = 0; kki < 2; ++kki) {
#pragma unroll
            for (int nt = 0; nt < 8; ++nt) {
                bf16x8 b = ldfrag(&s_w1[(nt * 16 + lr) * SW1 + kki * 32 + quad * 8]);
                accA[0][nt] = __builtin_amdgcn_mfma_f32_16x16x32_bf16(afr[0][kki].v, b, accA[0][nt], 0, 0, 0);
                accA[1][nt] = __builtin_amdgcn_mfma_f32_16x16x32_bf16(afr[1][kki].v, b, accA[1][nt], 0, 0, 0);
            }
        }
#pragma unroll
        for (int mt = 0; mt < 2; ++mt) {
            int r0 = m0 + mt * 16 + quad * 4;
            u16* tp0 = &s_t1[r0 * SA + lr];
#pragma unroll
            for (int nt = 0; nt < 8; ++nt) {
                int col = nt * 16;
                float bb = b1[l * 128 + col + lr];
                u32 p01 = pkbf(silu_f(accA[mt][nt][0] + bb),
                               silu_f(accA[mt][nt][1] + bb));
                u32 p23 = pkbf(silu_f(accA[mt][nt][2] + bb),
                               silu_f(accA[mt][nt][3] + bb));
                u16* tp = tp0 + col;
                tp[0]      = (u16)p01;
                tp[SA]     = (u16)(p01 >> 16);
                tp[2 * SA] = (u16)p23;
                tp[3 * SA] = (u16)(p23 >> 16);
            }
        }
    }
    // no barrier: Phase B reads only this wave's own 32 t1 rows
    {
        f32x4 accB[2][8];
#pragma unroll
        for (int mt = 0; mt < 2; ++mt)
#pragma unroll
            for (int nt = 0; nt < 8; ++nt) accB[mt][nt] = (f32x4){0.f, 0.f, 0.f, 0.f};
#pragma unroll
        for (int kk = 0; kk < 128; kk += 32) {
            bf16x8 a0 = ldfrag(&s_t1[(m0 + lr)      * SA + kk + quad * 8]);
            bf16x8 a1 = ldfrag(&s_t1[(m0 + 16 + lr) * SA + kk + quad * 8]);
#pragma unroll
            for (int nt = 0; nt < 8; ++nt) {
                bf16x8 b = ldfrag(&s_w2[(nt * 16 + lr) * SA + kk + quad * 8]);
                accB[0][nt] = __builtin_amdgcn_mfma_f32_16x16x32_bf16(a0, b, accB[0][nt], 0, 0, 0);
                accB[1][nt] = __builtin_amdgcn_mfma_f32_16x16x32_bf16(a1, b, accB[1][nt], 0, 0, 0);
            }
        }
        const float dstep = 10.0f / (float)(NTAB - 1);
#pragma unroll
        for (int mt = 0; mt < 2; ++mt) {
            int r0 = m0 + mt * 16 + quad * 4;
            float cv[4];
#pragma unroll
            for (int r = 0; r < 4; ++r) {
                float d = (float)(rbase + r0 + r) * dstep;
                cv[r] = 0.5f * (cosf(d * 3.14159265f / 10.0f) + 1.0f);
            }
#pragma unroll
            for (int nt = 0; nt < 8; ++nt) {
                int col = nt * 16 + lr;
                float bb = b2[l * 128 + col];
#pragma unroll
                for (int r = 0; r < 4; ++r) {
                    float val = (accB[mt][nt][r] + bb) * cv[r];
                    float oth = __shfl_xor(val, 1, 64);
                    if ((lr & 1) == 0) {
                        int row = rbase + r0 + r;
                        pk[((size_t)l * NTAB + row) * 64 + (col >> 1)] =
                            pkbf(val, oth);
                    }
                }
            }
        }
    }
}

// ---------------------------------------------------------------------------
// K3a: initial gemm0 (unchanged).
// ---------------------------------------------------------------------------
__launch_bounds__(256)
__global__ void gemm0_kernel(const int* __restrict__ z,
                             const float* __restrict__ emb,
                             const u16* __restrict__ Bt,
                             const float* __restrict__ bias,
                             u16* __restrict__ xjb) {
    __shared__ u16 s_a[16 * SA];
    __shared__ float s_bias[128];
    int tid = threadIdx.x;
    int row0 = blockIdx.x * 16;
#pragma unroll
    for (int p = 0; p < 2; ++p) {
        int q = tid + p * 256;
        int r = q >> 5, c4 = (q & 31) * 4;
        const float* src = emb + (size_t)z[row0 + r] * 128;
        float4 v = *(const float4*)(src + c4);
        u32* dd = (u32*)&s_a[r * SA + c4];
        dd[0] = pkbf(v.x, v.y); dd[1] = pkbf(v.z, v.w);
    }
    if (tid < 128) s_bias[tid] = bias[tid];
    __syncthreads();
    int wv = tid >> 6, lane = tid & 63;
    int quad = lane >> 4, lr = lane & 15;
    int n0 = wv * 32;
    f32x4 acc[2];
#pragma unroll
    for (int nt = 0; nt < 2; ++nt) acc[nt] = (f32x4){0.f, 0.f, 0.f, 0.f};
#pragma unroll
    for (int kk = 0; kk < 128; kk += 32) {
        bf16x8 a = ldfrag(&s_a[lr * SA + kk + quad * 8]);
#pragma unroll
        for (int nt = 0; nt < 2; ++nt) {
            bf16x8 b = ldfrag(Bt + (n0 + nt * 16 + lr) * 128 + kk + quad * 8);
            acc[nt] = __builtin_amdgcn_mfma_f32_16x16x32_bf16(a, b, acc[nt], 0, 0, 0);
        }
    }
#pragma unroll
    for (int nt = 0; nt < 2; ++nt)
#pragma unroll
        for (int r = 0; r < 4; ++r) {
            int col = n0 + nt * 16 + lr;
            xjb[(size_t)(row0 + quad * 4 + r) * 128 + col] =
                f2bf(acc[nt][r] + s_bias[col]);
        }
}

// ---------------------------------------------------------------------------
// K4c: aggregate — standalone, 1 receiver/wave, 2048 blocks. Edge descriptors
// preloaded to registers (si[lane], si[64+lane]); per-edge (sx,sy) via
// v_readlane broadcast (wave-uniform index) so pk/xjb loads have NO memory
// dependency. Depth-2 software pipeline: 16 loads in flight per wave.
// XCD-chunked swizzle keeps a graph's receivers on one XCD's L2.
// ---------------------------------------------------------------------------
#define AGG_ISSUE(T, X, base, ev)                                              \
    {                                                                          \
        _Pragma("unroll") for (int q = 0; q < 8; ++q) {                        \
            int e = (base) + q;                                                \
            int sx = __builtin_amdgcn_readlane((ev).x, e & 63);                \
            int sy = __builtin_amdgcn_readlane((ev).y, e & 63);                \
            T[q] = pk[(size_t)sy * 64 + lane];                                 \
            X[q] = *(const u32*)(xjb + (size_t)sx * 128 + c2);                 \
        }                                                                      \
    }

#define AGG_COMPUTE(T, X)                                                      \
    {                                                                          \
        _Pragma("unroll") for (int q = 0; q < 8; ++q) {                        \
            float v0 = bf2f((u16)T[q]) * bf2f((u16)X[q]);                      \
            float v1 = bf2f((u16)(T[q] >> 16)) * bf2f((u16)(X[q] >> 16));      \
            switch (q & 3) {                                                   \
                case 0: a0 += v0; a1 += v1; break;                             \
                case 1: b0 += v0; b1 += v1; break;                             \
                case 2: c0 += v0; c1 += v1; break;                             \
                default: d0 += v0; d1 += v1; break;                            \
            }                                                                  \
        }                                                                      \
    }

__launch_bounds__(256, 4)
__global__ void agg_kernel(const int* __restrict__ rev_cnt,
                           const int2* __restrict__ rev_si,
                           const u32* __restrict__ pk,
                           const u16* __restrict__ xjb,
                           float* __restrict__ agg) {
    int bid = ((blockIdx.x & 7) << 8) | (blockIdx.x >> 3);   // XCD-chunked
    int j = bid * 4 + (threadIdx.x >> 6);
    int lane = threadIdx.x & 63;
    int deg = rev_cnt[j];
    const int2* si = rev_si + (size_t)j * 128;
    int c2 = lane * 2;
    // preload all possible edge descriptors (poison beyond deg is never used)
    int2 e0 = si[lane];
    int2 e1 = si[64 + lane];
    float a0 = 0.f, a1 = 0.f, b0 = 0.f, b1 = 0.f;
    float c0 = 0.f, c1 = 0.f, d0 = 0.f, d1 = 0.f;
    u32 tA[8], xA[8], tB[8], xB[8];
    int ng = deg >> 3;
    if (ng > 0) {
        AGG_ISSUE(tA, xA, 0, e0);
        int g = 1;
        for (; g + 1 < ng; g += 2) {
            int2 evB = (g < 8) ? e0 : e1;
            AGG_ISSUE(tB, xB, g * 8, evB);
            AGG_COMPUTE(tA, xA);
            int2 evA = ((g + 1) < 8) ? e0 : e1;
            AGG_ISSUE(tA, xA, (g + 1) * 8, evA);
            AGG_COMPUTE(tB, xB);
        }
        if (g < ng) {
            int2 evB = (g < 8) ? e0 : e1;
            AGG_ISSUE(tB, xB, g * 8, evB);
            AGG_COMPUTE(tA, xA);
            AGG_COMPUTE(tB, xB);
        } else {
            AGG_COMPUTE(tA, xA);
        }
    }
    for (int it = ng * 8; it < deg; ++it) {
        int2 ev = (it < 64) ? e0 : e1;
        int sx = __builtin_amdgcn_readlane(ev.x, it & 63);
        int sy = __builtin_amdgcn_readlane(ev.y, it & 63);
        u32 t = pk[(size_t)sy * 64 + lane];
        u32 x = *(const u32*)(xjb + (size_t)sx * 128 + c2);
        a0 += bf2f((u16)t) * bf2f((u16)x);
        a1 += bf2f((u16)(t >> 16)) * bf2f((u16)(x >> 16));
    }
    float2 r;
    r.x = (a0 + b0) + (c0 + d0);
    r.y = (a1 + b1) + (c1 + d1);
    *(float2*)(agg + (size_t)j * 128 + c2) = r;
}

// ---------------------------------------------------------------------------
// K3b: layer tail — h += silu(agg @ l2w + b2) [hi/lo split A]; then (unless
// LAST) xj(l+1) = h_new @ l1w(l+1) + b1(l+1). LAST=1 fuses the output head
// (reads s_h directly) and finalize via last-block ticket. EMB=1: h_old=emb[z].
// ---------------------------------------------------------------------------
template <int EMB, int LAST>
__launch_bounds__(256)
__global__ void layer_tail_kernel(const float* __restrict__ agg,
                                  float* __restrict__ h,
                                  const int* __restrict__ z,
                                  const float* __restrict__ emb,
                                  const u16* __restrict__ B2t,
                                  const float* __restrict__ b2,
                                  const u16* __restrict__ B1n,
                                  const float* __restrict__ b1n,
                                  u16* __restrict__ xjb,
                                  const float* __restrict__ ow1,
                                  const float* __restrict__ ob1,
                                  const float* __restrict__ ow2,
                                  const float* __restrict__ ob2,
                                  float* __restrict__ gsum,
                                  int* __restrict__ done_cnt,
                                  void* __restrict__ out,
                                  const int* __restrict__ flag) {
    __shared__ u16 s_ahi[16 * SA];
    __shared__ u16 s_alo[16 * SA];
    __shared__ float s_h[16 * SH];
    __shared__ float s_b2[128], s_b1[128];
    __shared__ float s_w[LAST ? 128 * 64 : 1];
    __shared__ float s_sum;
    __shared__ int s_last;
    int tid = threadIdx.x;
    int row0 = blockIdx.x * 16;
#pragma unroll
    for (int p = 0; p < 2; ++p) {
        int q = tid + p * 256;
        int r = q >> 5, c4 = (q & 31) * 4;
        float4 v = *(const float4*)(agg + (size_t)(row0 + r) * 128 + c4);
        u32 h0 = pkbf(v.x, v.y), h1 = pkbf(v.z, v.w);
        u32* hd = (u32*)&s_ahi[r * SA + c4];
        hd[0] = h0; hd[1] = h1;
        u32 l0 = pkbf(v.x - bf2f((u16)h0), v.y - bf2f((u16)(h0 >> 16)));
        u32 l1 = pkbf(v.z - bf2f((u16)h1), v.w - bf2f((u16)(h1 >> 16)));
        u32* ld = (u32*)&s_alo[r * SA + c4];
        ld[0] = l0; ld[1] = l1;
    }
    if (tid < 128) {
        s_b2[tid] = b2[tid];
        if (!LAST) s_b1[tid] = b1n[tid];
    }
    if (LAST) {
        if (tid == 0) s_sum = 0.0f;
        const float4* src = (const float4*)ow1;
        float4* dst = (float4*)s_w;
#pragma unroll
        for (int p = 0; p < 8; ++p) dst[tid + p * 256] = src[tid + p * 256];
    }
    __syncthreads();

    int wv = tid >> 6, lane = tid & 63;
    int quad = lane >> 4, lr = lane & 15;
    int n0 = wv * 32;

    f32x4 acc[2];
#pragma unroll
    for (int nt = 0; nt < 2; ++nt) acc[nt] = (f32x4){0.f, 0.f, 0.f, 0.f};
#pragma unroll
    for (int kk = 0; kk < 128; kk += 32) {
        bf16x8 ah = ldfrag(&s_ahi[lr * SA + kk + quad * 8]);
        bf16x8 al = ldfrag(&s_alo[lr * SA + kk + quad * 8]);
#pragma unroll
        for (int nt = 0; nt < 2; ++nt) {
            bf16x8 b = ldfrag(B2t + (n0 + nt * 16 + lr) * 128 + kk + quad * 8);
            acc[nt] = __builtin_amdgcn_mfma_f32_16x16x32_bf16(ah, b, acc[nt], 0, 0, 0);
            acc[nt] = __builtin_amdgcn_mfma_f32_16x16x32_bf16(al, b, acc[nt], 0, 0, 0);
        }
    }
#pragma unroll
    for (int nt = 0; nt < 2; ++nt)
#pragma unroll
        for (int r = 0; r < 4; ++r) {
            int row = quad * 4 + r;
            int col = n0 + nt * 16 + lr;
            size_t off = (size_t)(row0 + row) * 128 + col;
            float hold = EMB ? emb[(size_t)z[row0 + row] * 128 + col] : h[off];
            float hn = hold + silu_f(acc[nt][r] + s_b2[col]);
            if (!LAST) h[off] = hn;
            s_h[row * SH + col] = hn;
        }
    __syncthreads();

    if (!LAST) {
        f32x4 ac2[2];
#pragma unroll
        for (int nt = 0; nt < 2; ++nt) ac2[nt] = (f32x4){0.f, 0.f, 0.f, 0.f};
#pragma unroll
        for (int kk = 0; kk < 128; kk += 32) {
            const float* ap = &s_h[lr * SH + kk + quad * 8];
            float4 v0 = *(const float4*)ap;
            float4 v1 = *(const float4*)(ap + 4);
            U8 a;
            a.w[0] = pkbf(v0.x, v0.y); a.w[1] = pkbf(v0.z, v0.w);
            a.w[2] = pkbf(v1.x, v1.y); a.w[3] = pkbf(v1.z, v1.w);
#pragma unroll
            for (int nt = 0; nt < 2; ++nt) {
                bf16x8 b = ldfrag(B1n + (n0 + nt * 16 + lr) * 128 + kk + quad * 8);
                ac2[nt] = __builtin_amdgcn_mfma_f32_16x16x32_bf16(a.v, b, ac2[nt], 0, 0, 0);
            }
        }
#pragma unroll
        for (int nt = 0; nt < 2; ++nt)
#pragma unroll
            for (int r = 0; r < 4; ++r) {
                int col = n0 + nt * 16 + lr;
                xjb[(size_t)(row0 + quad * 4 + r) * 128 + col] =
                    f2bf(ac2[nt][r] + s_b1[col]);
            }
    } else {
        // output head from s_h, then last-block finalize
        int atom = tid >> 4, cg = tid & 15;
        const float* hr = &s_h[atom * SH];
        const float4* w4 = (const float4*)s_w;
        float4 a4 = {0.f, 0.f, 0.f, 0.f};
#pragma unroll 8
        for (int f = 0; f < 128; ++f) {
            float hv = hr[f];
            float4 w = w4[f * 16 + cg];
            a4.x += hv * w.x; a4.y += hv * w.y;
            a4.z += hv * w.z; a4.w += hv * w.w;
        }
        int c0i = cg * 4;
        float v = silu_f(a4.x + ob1[c0i + 0]) * ow2[c0i + 0]
                + silu_f(a4.y + ob1[c0i + 1]) * ow2[c0i + 1]
                + silu_f(a4.z + ob1[c0i + 2]) * ow2[c0i + 2]
                + silu_f(a4.w + ob1[c0i + 3]) * ow2[c0i + 3];
        v += __shfl_xor(v, 1, 64);
        v += __shfl_xor(v, 2, 64);
        v += __shfl_xor(v, 4, 64);
        v += __shfl_xor(v, 8, 64);
        if ((tid & 15) == 0) atomicAdd(&s_sum, v + ob2[0]);
        __syncthreads();
        if (tid == 0) {
            atomicAdd(&gsum[row0 >> 7], s_sum);
            __threadfence();
            int tk = __hip_atomic_fetch_add(done_cnt, 1, __ATOMIC_ACQ_REL,
                                            __HIP_MEMORY_SCOPE_AGENT);
            s_last = (tk == (NATOMS / 16) - 1);
        }
        __syncthreads();
        if (s_last && tid < GRAPHS) {
            float g = __hip_atomic_load(&gsum[tid], __ATOMIC_RELAXED,
                                        __HIP_MEMORY_SCOPE_AGENT);
            if (*flag) ((float*)out)[tid] = g;
            else       ((u16*)out)[tid]   = f2bf(g);
        }
    }
}

// ---------------------------------------------------------------------------
extern "C" void kernel_launch(void* const* d_in, const int* in_sizes, int n_in,
                              void* d_out, int out_size, void* d_ws, size_t ws_size,
                              hipStream_t stream) {
    const void* pos  = d_in[0];
    const int*  z    = (const int*)d_in[1];
    // d_in[2] = batch (implicit: graph = i >> 7)
    const void* emb  = d_in[3];
    const void* mw1  = d_in[4];
    const void* mb1  = d_in[5];
    const void* mw2  = d_in[6];
    const void* mb2  = d_in[7];
    const void* l1w  = d_in[8];
    const void* l1b  = d_in[9];
    const void* l2w  = d_in[10];
    const void* l2b  = d_in[11];
    const void* ow1  = d_in[12];
    const void* ob1  = d_in[13];
    const void* ow2  = d_in[14];
    const void* ob2  = d_in[15];

    char* ws = (char*)d_ws;
    const size_t KB = 1024, MB = 1048576;
    int*   w_flag  = (int*)  (ws);
    int*   w_done  = (int*)  (ws + 64);
    float* c_emb   = (float*)(ws + 112 * KB);
    float* c_mb1   = (float*)(ws + 168 * KB);
    float* c_mb2   = (float*)(ws + 176 * KB);
    float* c_l1b   = (float*)(ws + 184 * KB);
    float* c_l2b   = (float*)(ws + 192 * KB);
    float* c_ow1   = (float*)(ws + 200 * KB);
    float* c_ob1   = (float*)(ws + 236 * KB);
    float* c_ow2   = (float*)(ws + 240 * KB);
    float* c_ob2   = (float*)(ws + 244 * KB);
    float* w_gsum  = (float*)(ws + 248 * KB);
    u16*   c_l1wt  = (u16*)  (ws + 256 * KB);   // 192 KB
    u16*   c_l2wt  = (u16*)  (ws + 448 * KB);   // 192 KB
    u16*   c_mw2t  = (u16*)  (ws + 640 * KB);   // 192 KB
    u16*   c_mw1t  = (u16*)  (ws + 832 * KB);   // 96 KB
    int*   rev_cnt = (int*)  (ws + 2  * MB);    // 32 KB
    int2*  rev_si  = (int2*) (ws + 3  * MB);    // 8 MB
    float* w_h     = (float*)(ws + 11 * MB);    // 4 MB
    u16*   w_xjb   = (u16*)  (ws + 15 * MB);    // 2 MB
    float* w_agg   = (float*)(ws + 17 * MB);    // 4 MB
    u32*   w_pk    = (u32*)  (ws + 21 * MB);    // 6 MB

    probe_kernel<<<1, 256, 0, stream>>>((const u16*)emb, w_flag, rev_cnt,
                                        w_gsum, w_done);

    IngestDesc dsc;
    const void* srcs[NARR] = {emb, mb1, mb2, l1b, l2b, ow1, ob1, ow2, ob2};
    void* dsts[NARR] = {c_emb, c_mb1, c_mb2, c_l1b, c_l2b, c_ow1, c_ob1,
                        c_ow2, c_ob2};
    int ns_[NARR] = {12800, 768, 768, 768, 768, 8192, 64, 64, 1};
    int total = 0;
    for (int a = 0; a < NARR; ++a) {
        dsc.src[a] = srcs[a]; dsc.dst[a] = dsts[a]; dsc.n[a] = ns_[a];
        total += ns_[a];
    }
    int nb_ing = (total + 255) / 256;
    setup_kernel<<<NB_BUILD + NB_PREP + nb_ing, 256, 0, stream>>>(
        pos, l1w, l2w, mw2, mw1, c_l1wt, c_l2wt, c_mw2t, c_mw1t,
        dsc, total, w_flag, rev_cnt, rev_si);

    vtab_kernel<<<LAYERS * NTAB / 128, 256, 0, stream>>>(
        c_mw1t, c_mw2t, c_mb1, c_mb2, w_pk);

    gemm0_kernel<<<NATOMS / 16, 256, 0, stream>>>(z, c_emb, c_l1wt, c_l1b, w_xjb);

    for (int l = 0; l < LAYERS; ++l) {
        const u16* B2 = c_l2wt + (size_t)l * 16384;
        const float* b2 = c_l2b + (size_t)l * 128;
        const u16* B1n = c_l1wt + (size_t)(l + 1) * 16384;
        const float* b1n = c_l1b + (size_t)(l + 1) * 128;
        const u32* pkl = w_pk + (size_t)l * NTAB * 64;

        agg_kernel<<<NATOMS / 4, 256, 0, stream>>>(rev_cnt, rev_si, pkl,
                                                   w_xjb, w_agg);
        if (l == 0)
            layer_tail_kernel<1, 0><<<NATOMS / 16, 256, 0, stream>>>(
                w_agg, w_h, z, c_emb, B2, b2, B1n, b1n, w_xjb,
                nullptr, nullptr, nullptr, nullptr, nullptr, nullptr, nullptr,
                nullptr);
        else if (l < LAYERS - 1)
            layer_tail_kernel<0, 0><<<NATOMS / 16, 256, 0, stream>>>(
                w_agg, w_h, z, c_emb, B2, b2, B1n, b1n, w_xjb,
                nullptr, nullptr, nullptr, nullptr, nullptr, nullptr, nullptr,
                nullptr);
        else
            layer_tail_kernel<0, 1><<<NATOMS / 16, 256, 0, stream>>>(
                w_agg, w_h, z, c_emb, B2, b2, nullptr, nullptr, nullptr,
                c_ow1, c_ob1, c_ow2, c_ob2, w_gsum, w_done, d_out, w_flag);
    }
}